// Round 17
// baseline (507.169 us; speedup 1.0000x reference)
//
#include <hip/hip_runtime.h>
#include <hip/hip_bf16.h>

#define PTOT   32768
#define KNB    16
#define NCLOUD 16
#define OUTC   512
#define A1S    168   // sa2 A1 row stride in ushort (336 B, 16B-aligned)
#define A2S    264   // sa2 A2 row stride in ushort (528 B, 16B-aligned)

typedef __attribute__((ext_vector_type(8)))  short v8bf;
typedef __attribute__((ext_vector_type(16))) float v16f;

__device__ __forceinline__ unsigned short f2b(float v) {
    __hip_bfloat16 h = __float2bfloat16(v);
    return *reinterpret_cast<unsigned short*>(&h);
}
__device__ __forceinline__ unsigned pk2(float a, float b) {
    return (unsigned)f2b(a) | ((unsigned)f2b(b) << 16);
}
__device__ __forceinline__ unsigned fenc(float f) {
    unsigned u = __float_as_uint(f);
    return (u & 0x80000000u) ? ~u : (u | 0x80000000u);
}
__device__ __forceinline__ float fdec(unsigned u) {
    unsigned b = (u & 0x80000000u) ? (u & 0x7FFFFFFFu) : ~u;
    return __uint_as_float(b);
}
__device__ __forceinline__ v16f zero16() {
    v16f z;
    #pragma unroll
    for (int i = 0; i < 16; ++i) z[i] = 0.0f;
    return z;
}

// ======= sa1 (MFMA) + absorbed prep: block = 8 points (two 4-pt groups) =====
// W1/W2 fragments built directly from global fp32 (no weight images needed).
// Blocks 0..671 also transpose W3->W3s / W4->W4s (256 elems each);
// block 4095 zero-inits encbuf + completion counter for sa2's fused finalize.
__global__ __launch_bounds__(256) void sa1_kernel(
    const float* __restrict__ pos, const int* __restrict__ nbr,
    const float* __restrict__ W1, const float* __restrict__ b1,
    const float* __restrict__ W2, const float* __restrict__ b2,
    const float* __restrict__ W3, const float* __restrict__ W4,
    unsigned short* __restrict__ W3s, unsigned short* __restrict__ W4s,
    unsigned* __restrict__ encbuf, unsigned* __restrict__ ctr,
    unsigned short* __restrict__ x1b)
{
    __shared__ unsigned short A1d[64 * 16];   // 2 KB
    __shared__ unsigned short A2[64 * 72];    // 9 KB
    const int tid  = threadIdx.x;
    const int lane = tid & 63;
    const int wave = tid >> 6;
    const int l31  = lane & 31;
    const int h    = lane >> 5;

    // ---- absorbed prep: W3s/W4s k-major bf16 images (blocks 0..671)
    {
        int ip = blockIdx.x * 256 + tid;
        if (ip < 40960) {                        // W3s[(c2*256+n)*8+j] = W3[c2*8+j][n]
            int j = ip & 7, n = (ip >> 3) & 255, c2 = ip >> 11;
            int k = c2 * 8 + j;
            W3s[ip] = f2b(k < 131 ? W3[k * 256 + n] : 0.0f);
        }
        int i2 = ip - 40960;
        if (i2 >= 0 && i2 < 131072) {            // W4s[(c2*512+n)*8+j] = W4[c2*8+j][n]
            int j = i2 & 7, n = (i2 >> 3) & 511, c2 = i2 >> 12;
            int k = c2 * 8 + j;
            W4s[i2] = f2b(W4[k * 512 + n]);
        }
        if (blockIdx.x == 4095) {                // encbuf + counter init
            for (int i = tid; i < NCLOUD * OUTC; i += 256) encbuf[i] = 0u;
            if (tid == 0) *ctr = 0u;
        }
    }

    // ---- group-invariant weight fragments, built from global fp32
    const int c1 = (wave >> 1) * 32 + l31;
    v8bf b1f;
    #pragma unroll
    for (int i = 0; i < 8; ++i) b1f[i] = 0;
    if (h == 0) {   // k=0..2 real, rest zero; h=1 half (k=8..15) all zero
        b1f[0] = (short)f2b(W1[c1]);
        b1f[1] = (short)f2b(W1[64 + c1]);
        b1f[2] = (short)f2b(W1[128 + c1]);
    }
    const float b1v = b1[c1];
    const int cW2 = wave * 32 + l31;
    v8bf B2[4];
    #pragma unroll
    for (int kc = 0; kc < 4; ++kc)
        #pragma unroll
        for (int j = 0; j < 8; ++j)
            B2[kc][j] = (short)f2b(W2[(kc * 16 + h * 8 + j) * 128 + cW2]);
    const float b2v = b2[cW2];

    #pragma unroll
    for (int g = 0; g < 2; ++g) {
        const int p0 = blockIdx.x * 8 + g * 4;
        __syncthreads();   // previous group's A2 reads done before restage
        if (tid < 64) {
            int r = tid;
            int j = nbr[p0 * KNB + r];
            int p = p0 + (r >> 4);
            v8bf z;
            #pragma unroll
            for (int i = 0; i < 8; ++i) z[i] = 0;
            v8bf dv = z;
            dv[0] = (short)f2b(pos[j * 3 + 0] - pos[p * 3 + 0]);
            dv[1] = (short)f2b(pos[j * 3 + 1] - pos[p * 3 + 1]);
            dv[2] = (short)f2b(pos[j * 3 + 2] - pos[p * 3 + 2]);
            *(v8bf*)(A1d + r * 16)     = dv;
            *(v8bf*)(A1d + r * 16 + 8) = z;
        }
        __syncthreads();

        {
            v8bf a = *(const v8bf*)(A1d + ((wave & 1) * 32 + l31) * 16 + h * 8);
            v16f acc = __builtin_amdgcn_mfma_f32_32x32x16_bf16(a, b1f, zero16(), 0, 0, 0);
            #pragma unroll
            for (int r = 0; r < 16; ++r) {
                int row = (wave & 1) * 32 + (r & 3) + 8 * (r >> 2) + 4 * h;
                A2[row * 72 + c1] = f2b(fmaxf(acc[r] + b1v, 0.0f));
            }
        }
        __syncthreads();

        #pragma unroll
        for (int rt = 0; rt < 2; ++rt) {
            v16f acc = zero16();
            #pragma unroll
            for (int kc = 0; kc < 4; ++kc) {
                v8bf a = *(const v8bf*)(A2 + (rt * 32 + l31) * 72 + kc * 16 + h * 8);
                acc = __builtin_amdgcn_mfma_f32_32x32x16_bf16(a, B2[kc], acc, 0, 0, 0);
            }
            float ma = acc[0], mb = acc[8];
            #pragma unroll
            for (int r = 1; r < 8; ++r) { ma = fmaxf(ma, acc[r]); mb = fmaxf(mb, acc[8 + r]); }
            ma = fmaxf(ma, __shfl_xor(ma, 32));
            mb = fmaxf(mb, __shfl_xor(mb, 32));
            int p = p0 + rt * 2 + h;
            float m = h ? mb : ma;
            x1b[p * 128 + wave * 32 + l31] = f2b(m + b2v);
        }
    }
}

// ==== sa2 (MFMA): R8-proven body + fused last-block finalize ================
__global__ __launch_bounds__(256) void sa2_kernel(
    const float* __restrict__ pos, const int* __restrict__ nbr,
    const int* __restrict__ batch,
    const unsigned short* __restrict__ W3s, const float* __restrict__ b3,
    const unsigned short* __restrict__ W4s, const float* __restrict__ b4,
    const unsigned short* __restrict__ x1b, unsigned* __restrict__ encbuf,
    unsigned* __restrict__ ctr, float* __restrict__ out)
{
    __shared__ unsigned short S[128 * A2S];   // 67584 B: A1 (stride A1S) overlaid
    const int tid  = threadIdx.x;
    const int lane = tid & 63;
    const int wave = tid >> 6;
    const int l31  = lane & 31;
    const int h    = lane >> 5;
    const int p0   = blockIdx.x * 8;

    const float b3v0 = b3[(wave * 2 + 0) * 32 + l31];
    const float b3v1 = b3[(wave * 2 + 1) * 32 + l31];

    // ---- stage A1: 128 rows = (point, nbr); 2 threads/row, 128 B each
    {
        int r = tid >> 1, q = tid & 1;
        int j = nbr[p0 * KNB + r];
        const uint4* src = (const uint4*)(x1b + j * 128 + q * 64);
        uint4* dst = (uint4*)(S + r * A1S + q * 64);
        #pragma unroll
        for (int i = 0; i < 8; ++i) dst[i] = src[i];
    }
    if (tid < 128) {
        int r = tid;
        int j = nbr[p0 * KNB + r];
        int p = p0 + (r >> 4);
        v8bf z;
        #pragma unroll
        for (int i = 0; i < 8; ++i) z[i] = 0;
        v8bf dv = z;
        dv[0] = (short)f2b(pos[j * 3 + 0] - pos[p * 3 + 0]);
        dv[1] = (short)f2b(pos[j * 3 + 1] - pos[p * 3 + 1]);
        dv[2] = (short)f2b(pos[j * 3 + 2] - pos[p * 3 + 2]);
        *(v8bf*)(S + r * A1S + 128) = dv;
        *(v8bf*)(S + r * A1S + 136) = z;
    }
    __syncthreads();

    // ---- GEMM1: kc-streamed B, looped over 2 row-tile-pairs; kc=9 pad skipped
    const int n1a = (wave * 2 + 0) * 32 + l31;
    const int n1b = (wave * 2 + 1) * 32 + l31;
    unsigned stA[2][16], stB[2][16];   // [rtp][..] ci=0 / ci=1
    #pragma unroll
    for (int rtp = 0; rtp < 2; ++rtp) {
        v16f g00 = zero16(), g01 = zero16(), g10 = zero16(), g11 = zero16();
        #pragma unroll
        for (int kc = 0; kc < 9; ++kc) {
            v8bf a0 = *(const v8bf*)(S + (rtp * 64 + l31)      * A1S + kc * 16 + h * 8);
            v8bf a1 = *(const v8bf*)(S + (rtp * 64 + 32 + l31) * A1S + kc * 16 + h * 8);
            int c2 = kc * 2 + h;
            v8bf B0 = *(const v8bf*)(W3s + ((c2 * 256 + n1a) << 3));
            v8bf B1 = *(const v8bf*)(W3s + ((c2 * 256 + n1b) << 3));
            g00 = __builtin_amdgcn_mfma_f32_32x32x16_bf16(a0, B0, g00, 0, 0, 0);
            g10 = __builtin_amdgcn_mfma_f32_32x32x16_bf16(a1, B0, g10, 0, 0, 0);
            g01 = __builtin_amdgcn_mfma_f32_32x32x16_bf16(a0, B1, g01, 0, 0, 0);
            g11 = __builtin_amdgcn_mfma_f32_32x32x16_bf16(a1, B1, g11, 0, 0, 0);
        }
        #pragma unroll
        for (int i = 0; i < 8; ++i) {
            stA[rtp][i]     = pk2(fmaxf(g00[2*i] + b3v0, 0.0f), fmaxf(g00[2*i+1] + b3v0, 0.0f));
            stA[rtp][8 + i] = pk2(fmaxf(g10[2*i] + b3v0, 0.0f), fmaxf(g10[2*i+1] + b3v0, 0.0f));
            stB[rtp][i]     = pk2(fmaxf(g01[2*i] + b3v1, 0.0f), fmaxf(g01[2*i+1] + b3v1, 0.0f));
            stB[rtp][8 + i] = pk2(fmaxf(g11[2*i] + b3v1, 0.0f), fmaxf(g11[2*i+1] + b3v1, 0.0f));
        }
    }
    __syncthreads();   // all A1 reads complete — safe to overwrite with A2

    // ---- store A2 = bf16(relu(GEMM1)) row-major, stride A2S
    {
        const int c0 = (wave * 2 + 0) * 32 + l31;
        const int c1 = (wave * 2 + 1) * 32 + l31;
        #pragma unroll
        for (int rtp = 0; rtp < 2; ++rtp) {
            const int rb = rtp * 64;
            #pragma unroll
            for (int i = 0; i < 8; ++i) {
                int row = rb + ((2*i) & 3) + 8 * ((2*i) >> 2) + 4 * h;
                S[row * A2S + c0]        = (unsigned short)(stA[rtp][i] & 0xFFFF);
                S[(row + 1) * A2S + c0]  = (unsigned short)(stA[rtp][i] >> 16);
                S[(row + 32) * A2S + c0] = (unsigned short)(stA[rtp][8 + i] & 0xFFFF);
                S[(row + 33) * A2S + c0] = (unsigned short)(stA[rtp][8 + i] >> 16);
                S[row * A2S + c1]        = (unsigned short)(stB[rtp][i] & 0xFFFF);
                S[(row + 1) * A2S + c1]  = (unsigned short)(stB[rtp][i] >> 16);
                S[(row + 32) * A2S + c1] = (unsigned short)(stB[rtp][8 + i] & 0xFFFF);
                S[(row + 33) * A2S + c1] = (unsigned short)(stB[rtp][8 + i] >> 16);
            }
        }
    }
    __syncthreads();   // A2 ready

    // ---- GEMM2: ct-pair outer (B held, reused by both row-tile-pairs)
    const int cloud = batch[p0];
    #pragma unroll
    for (int cp = 0; cp < 2; ++cp) {
        const int ct0 = wave * 4 + cp * 2;
        const int n0 = ct0 * 32 + l31;
        const int n1 = (ct0 + 1) * 32 + l31;
        v8bf B2a[16], B2b[16];
        #pragma unroll
        for (int kc = 0; kc < 16; ++kc) {
            int c2 = kc * 2 + h;
            B2a[kc] = *(const v8bf*)(W4s + ((c2 * 512 + n0) << 3));
            B2b[kc] = *(const v8bf*)(W4s + ((c2 * 512 + n1) << 3));
        }
        float rm0 = -3.4e38f, rm1 = -3.4e38f;
        #pragma unroll
        for (int rtp = 0; rtp < 2; ++rtp) {
            v16f a00 = zero16(), a01 = zero16(), a10 = zero16(), a11 = zero16();
            #pragma unroll
            for (int kc = 0; kc < 16; ++kc) {
                v8bf a0 = *(const v8bf*)(S + (rtp * 64 + l31)      * A2S + kc * 16 + h * 8);
                v8bf a1 = *(const v8bf*)(S + (rtp * 64 + 32 + l31) * A2S + kc * 16 + h * 8);
                a00 = __builtin_amdgcn_mfma_f32_32x32x16_bf16(a0, B2a[kc], a00, 0, 0, 0);
                a10 = __builtin_amdgcn_mfma_f32_32x32x16_bf16(a1, B2a[kc], a10, 0, 0, 0);
                a01 = __builtin_amdgcn_mfma_f32_32x32x16_bf16(a0, B2b[kc], a01, 0, 0, 0);
                a11 = __builtin_amdgcn_mfma_f32_32x32x16_bf16(a1, B2b[kc], a11, 0, 0, 0);
            }
            #pragma unroll
            for (int r = 0; r < 16; ++r) {
                rm0 = fmaxf(rm0, fmaxf(a00[r], a10[r]));
                rm1 = fmaxf(rm1, fmaxf(a01[r], a11[r]));
            }
        }
        rm0 = fmaxf(rm0, __shfl_xor(rm0, 32));
        rm1 = fmaxf(rm1, __shfl_xor(rm1, 32));
        rm0 += b4[ct0 * 32 + l31];
        rm1 += b4[(ct0 + 1) * 32 + l31];
        if (lane < 32) {
            atomicMax(&encbuf[cloud * OUTC + ct0 * 32 + l31], fenc(rm0));
            atomicMax(&encbuf[cloud * OUTC + (ct0 + 1) * 32 + l31], fenc(rm1));
        }
    }

    // ---- fused finalize: last block decodes encbuf -> out
    __threadfence();   // make this block's atomics visible device-wide
    __syncthreads();
    unsigned* flag = (unsigned*)S;   // S dead after GEMM2
    if (tid == 0) {
        unsigned old = atomicAdd(ctr, 1u);
        *flag = (old == gridDim.x - 1) ? 1u : 0u;
    }
    __syncthreads();
    if (*flag) {
        for (int i = tid; i < NCLOUD * OUTC; i += 256) {
            unsigned e = atomicOr(&encbuf[i], 0u);   // device-scope atomic load
            out[i] = fdec(e);
        }
    }
}

extern "C" void kernel_launch(void* const* d_in, const int* in_sizes, int n_in,
                              void* d_out, int out_size, void* d_ws, size_t ws_size,
                              hipStream_t stream)
{
    const float* pos   = (const float*)d_in[0];
    const int*   nbr   = (const int*)  d_in[1];
    const int*   batch = (const int*)  d_in[2];
    const float* W1    = (const float*)d_in[3];
    const float* b1    = (const float*)d_in[4];
    const float* W2    = (const float*)d_in[5];
    const float* b2    = (const float*)d_in[6];
    const float* W3    = (const float*)d_in[7];
    const float* b3    = (const float*)d_in[8];
    const float* W4    = (const float*)d_in[9];
    const float* b4    = (const float*)d_in[10];

    unsigned short* x1b = (unsigned short*)d_ws;                          // 8 MB
    unsigned short* W3s = (unsigned short*)((char*)d_ws + 8388608);       // 80 KB
    unsigned short* W4s = (unsigned short*)((char*)d_ws + 8470528);       // 256 KB
    unsigned*    encbuf = (unsigned*)((char*)d_ws + 8732672);             // 32 KB
    unsigned*       ctr = (unsigned*)((char*)d_ws + 8765440);             // 4 B

    sa1_kernel<<<PTOT / 8, 256, 0, stream>>>(pos, nbr, W1, b1, W2, b2, W3, W4,
                                             W3s, W4s, encbuf, ctr, x1b);
    sa2_kernel<<<PTOT / 8, 256, 0, stream>>>(pos, nbr, batch, W3s, b3, W4s, b4,
                                             x1b, encbuf, ctr, (float*)d_out);
}

// Round 18
// 247.606 us; speedup vs baseline: 2.0483x; 2.0483x over previous
//
#include <hip/hip_runtime.h>
#include <hip/hip_bf16.h>

#define PTOT   32768
#define KNB    16
#define NCLOUD 16
#define OUTC   512
#define A1S    168   // sa2 A1 row stride in ushort (336 B, 16B-aligned)
#define A2S    264   // sa2 A2 row stride in ushort (528 B, 16B-aligned)

typedef __attribute__((ext_vector_type(8)))  short v8bf;
typedef __attribute__((ext_vector_type(16))) float v16f;

__device__ __forceinline__ unsigned short f2b(float v) {
    __hip_bfloat16 h = __float2bfloat16(v);
    return *reinterpret_cast<unsigned short*>(&h);
}
__device__ __forceinline__ unsigned pk2(float a, float b) {
    return (unsigned)f2b(a) | ((unsigned)f2b(b) << 16);
}
__device__ __forceinline__ unsigned fenc(float f) {
    unsigned u = __float_as_uint(f);
    return (u & 0x80000000u) ? ~u : (u | 0x80000000u);
}
__device__ __forceinline__ float fdec(unsigned u) {
    unsigned b = (u & 0x80000000u) ? (u & 0x7FFFFFFFu) : ~u;
    return __uint_as_float(b);
}
__device__ __forceinline__ v16f zero16() {
    v16f z;
    #pragma unroll
    for (int i = 0; i < 16; ++i) z[i] = 0.0f;
    return z;
}

// ======= sa1 (MFMA) + absorbed prep: block = 8 points (two 4-pt groups) =====
// W1/W2 fragments built directly from global fp32 (no weight images).
// Blocks 0..671 also transpose W3->W3s / W4->W4s; block 4095 zeroes encbuf.
// NO per-block device fences (R17 lesson: __threadfence per block = 2.5x
// slowdown from L2 writeback) — kernel-boundary release covers visibility.
__global__ __launch_bounds__(256) void sa1_kernel(
    const float* __restrict__ pos, const int* __restrict__ nbr,
    const float* __restrict__ W1, const float* __restrict__ b1,
    const float* __restrict__ W2, const float* __restrict__ b2,
    const float* __restrict__ W3, const float* __restrict__ W4,
    unsigned short* __restrict__ W3s, unsigned short* __restrict__ W4s,
    unsigned* __restrict__ encbuf,
    unsigned short* __restrict__ x1b)
{
    __shared__ unsigned short A1d[64 * 16];   // 2 KB
    __shared__ unsigned short A2[64 * 72];    // 9 KB
    const int tid  = threadIdx.x;
    const int lane = tid & 63;
    const int wave = tid >> 6;
    const int l31  = lane & 31;
    const int h    = lane >> 5;

    // ---- absorbed prep: W3s/W4s k-major bf16 images (blocks 0..671)
    {
        int ip = blockIdx.x * 256 + tid;
        if (ip < 40960) {                        // W3s[(c2*256+n)*8+j] = W3[c2*8+j][n]
            int j = ip & 7, n = (ip >> 3) & 255, c2 = ip >> 11;
            int k = c2 * 8 + j;
            W3s[ip] = f2b(k < 131 ? W3[k * 256 + n] : 0.0f);
        }
        int i2 = ip - 40960;
        if (i2 >= 0 && i2 < 131072) {            // W4s[(c2*512+n)*8+j] = W4[c2*8+j][n]
            int j = i2 & 7, n = (i2 >> 3) & 511, c2 = i2 >> 12;
            int k = c2 * 8 + j;
            W4s[i2] = f2b(W4[k * 512 + n]);
        }
        if (blockIdx.x == 4095) {                // encbuf init (fenc-domain -inf)
            for (int i = tid; i < NCLOUD * OUTC; i += 256) encbuf[i] = 0u;
        }
    }

    // ---- group-invariant weight fragments, built from global fp32
    const int c1 = (wave >> 1) * 32 + l31;
    v8bf b1f;
    #pragma unroll
    for (int i = 0; i < 8; ++i) b1f[i] = 0;
    if (h == 0) {   // k=0..2 real, rest zero; h=1 half (k=8..15) all zero
        b1f[0] = (short)f2b(W1[c1]);
        b1f[1] = (short)f2b(W1[64 + c1]);
        b1f[2] = (short)f2b(W1[128 + c1]);
    }
    const float b1v = b1[c1];
    const int cW2 = wave * 32 + l31;
    v8bf B2[4];
    #pragma unroll
    for (int kc = 0; kc < 4; ++kc)
        #pragma unroll
        for (int j = 0; j < 8; ++j)
            B2[kc][j] = (short)f2b(W2[(kc * 16 + h * 8 + j) * 128 + cW2]);
    const float b2v = b2[cW2];

    #pragma unroll
    for (int g = 0; g < 2; ++g) {
        const int p0 = blockIdx.x * 8 + g * 4;
        __syncthreads();   // previous group's A2 reads done before restage
        if (tid < 64) {
            int r = tid;
            int j = nbr[p0 * KNB + r];
            int p = p0 + (r >> 4);
            v8bf z;
            #pragma unroll
            for (int i = 0; i < 8; ++i) z[i] = 0;
            v8bf dv = z;
            dv[0] = (short)f2b(pos[j * 3 + 0] - pos[p * 3 + 0]);
            dv[1] = (short)f2b(pos[j * 3 + 1] - pos[p * 3 + 1]);
            dv[2] = (short)f2b(pos[j * 3 + 2] - pos[p * 3 + 2]);
            *(v8bf*)(A1d + r * 16)     = dv;
            *(v8bf*)(A1d + r * 16 + 8) = z;
        }
        __syncthreads();

        {
            v8bf a = *(const v8bf*)(A1d + ((wave & 1) * 32 + l31) * 16 + h * 8);
            v16f acc = __builtin_amdgcn_mfma_f32_32x32x16_bf16(a, b1f, zero16(), 0, 0, 0);
            #pragma unroll
            for (int r = 0; r < 16; ++r) {
                int row = (wave & 1) * 32 + (r & 3) + 8 * (r >> 2) + 4 * h;
                A2[row * 72 + c1] = f2b(fmaxf(acc[r] + b1v, 0.0f));
            }
        }
        __syncthreads();

        #pragma unroll
        for (int rt = 0; rt < 2; ++rt) {
            v16f acc = zero16();
            #pragma unroll
            for (int kc = 0; kc < 4; ++kc) {
                v8bf a = *(const v8bf*)(A2 + (rt * 32 + l31) * 72 + kc * 16 + h * 8);
                acc = __builtin_amdgcn_mfma_f32_32x32x16_bf16(a, B2[kc], acc, 0, 0, 0);
            }
            float ma = acc[0], mb = acc[8];
            #pragma unroll
            for (int r = 1; r < 8; ++r) { ma = fmaxf(ma, acc[r]); mb = fmaxf(mb, acc[8 + r]); }
            ma = fmaxf(ma, __shfl_xor(ma, 32));
            mb = fmaxf(mb, __shfl_xor(mb, 32));
            int p = p0 + rt * 2 + h;
            float m = h ? mb : ma;
            x1b[p * 128 + wave * 32 + l31] = f2b(m + b2v);
        }
    }
}

// ==== sa2 (MFMA): R16-proven body, byte-identical (no fence, no finalize) ===
__global__ __launch_bounds__(256) void sa2_kernel(
    const float* __restrict__ pos, const int* __restrict__ nbr,
    const int* __restrict__ batch,
    const unsigned short* __restrict__ W3s, const float* __restrict__ b3,
    const unsigned short* __restrict__ W4s, const float* __restrict__ b4,
    const unsigned short* __restrict__ x1b, unsigned* __restrict__ encbuf)
{
    __shared__ unsigned short S[128 * A2S];   // 67584 B: A1 (stride A1S) overlaid
    const int tid  = threadIdx.x;
    const int lane = tid & 63;
    const int wave = tid >> 6;
    const int l31  = lane & 31;
    const int h    = lane >> 5;
    const int p0   = blockIdx.x * 8;

    const float b3v0 = b3[(wave * 2 + 0) * 32 + l31];
    const float b3v1 = b3[(wave * 2 + 1) * 32 + l31];

    // ---- stage A1: 128 rows = (point, nbr); 2 threads/row, 128 B each
    {
        int r = tid >> 1, q = tid & 1;
        int j = nbr[p0 * KNB + r];
        const uint4* src = (const uint4*)(x1b + j * 128 + q * 64);
        uint4* dst = (uint4*)(S + r * A1S + q * 64);
        #pragma unroll
        for (int i = 0; i < 8; ++i) dst[i] = src[i];
    }
    if (tid < 128) {
        int r = tid;
        int j = nbr[p0 * KNB + r];
        int p = p0 + (r >> 4);
        v8bf z;
        #pragma unroll
        for (int i = 0; i < 8; ++i) z[i] = 0;
        v8bf dv = z;
        dv[0] = (short)f2b(pos[j * 3 + 0] - pos[p * 3 + 0]);
        dv[1] = (short)f2b(pos[j * 3 + 1] - pos[p * 3 + 1]);
        dv[2] = (short)f2b(pos[j * 3 + 2] - pos[p * 3 + 2]);
        *(v8bf*)(S + r * A1S + 128) = dv;
        *(v8bf*)(S + r * A1S + 136) = z;
    }
    __syncthreads();

    // ---- GEMM1: kc-streamed B, looped over 2 row-tile-pairs; kc=9 pad skipped
    const int n1a = (wave * 2 + 0) * 32 + l31;
    const int n1b = (wave * 2 + 1) * 32 + l31;
    unsigned stA[2][16], stB[2][16];   // [rtp][..] ci=0 / ci=1
    #pragma unroll
    for (int rtp = 0; rtp < 2; ++rtp) {
        v16f g00 = zero16(), g01 = zero16(), g10 = zero16(), g11 = zero16();
        #pragma unroll
        for (int kc = 0; kc < 9; ++kc) {
            v8bf a0 = *(const v8bf*)(S + (rtp * 64 + l31)      * A1S + kc * 16 + h * 8);
            v8bf a1 = *(const v8bf*)(S + (rtp * 64 + 32 + l31) * A1S + kc * 16 + h * 8);
            int c2 = kc * 2 + h;
            v8bf B0 = *(const v8bf*)(W3s + ((c2 * 256 + n1a) << 3));
            v8bf B1 = *(const v8bf*)(W3s + ((c2 * 256 + n1b) << 3));
            g00 = __builtin_amdgcn_mfma_f32_32x32x16_bf16(a0, B0, g00, 0, 0, 0);
            g10 = __builtin_amdgcn_mfma_f32_32x32x16_bf16(a1, B0, g10, 0, 0, 0);
            g01 = __builtin_amdgcn_mfma_f32_32x32x16_bf16(a0, B1, g01, 0, 0, 0);
            g11 = __builtin_amdgcn_mfma_f32_32x32x16_bf16(a1, B1, g11, 0, 0, 0);
        }
        #pragma unroll
        for (int i = 0; i < 8; ++i) {
            stA[rtp][i]     = pk2(fmaxf(g00[2*i] + b3v0, 0.0f), fmaxf(g00[2*i+1] + b3v0, 0.0f));
            stA[rtp][8 + i] = pk2(fmaxf(g10[2*i] + b3v0, 0.0f), fmaxf(g10[2*i+1] + b3v0, 0.0f));
            stB[rtp][i]     = pk2(fmaxf(g01[2*i] + b3v1, 0.0f), fmaxf(g01[2*i+1] + b3v1, 0.0f));
            stB[rtp][8 + i] = pk2(fmaxf(g11[2*i] + b3v1, 0.0f), fmaxf(g11[2*i+1] + b3v1, 0.0f));
        }
    }
    __syncthreads();   // all A1 reads complete — safe to overwrite with A2

    // ---- store A2 = bf16(relu(GEMM1)) row-major, stride A2S
    {
        const int c0 = (wave * 2 + 0) * 32 + l31;
        const int c1 = (wave * 2 + 1) * 32 + l31;
        #pragma unroll
        for (int rtp = 0; rtp < 2; ++rtp) {
            const int rb = rtp * 64;
            #pragma unroll
            for (int i = 0; i < 8; ++i) {
                int row = rb + ((2*i) & 3) + 8 * ((2*i) >> 2) + 4 * h;
                S[row * A2S + c0]        = (unsigned short)(stA[rtp][i] & 0xFFFF);
                S[(row + 1) * A2S + c0]  = (unsigned short)(stA[rtp][i] >> 16);
                S[(row + 32) * A2S + c0] = (unsigned short)(stA[rtp][8 + i] & 0xFFFF);
                S[(row + 33) * A2S + c0] = (unsigned short)(stA[rtp][8 + i] >> 16);
                S[row * A2S + c1]        = (unsigned short)(stB[rtp][i] & 0xFFFF);
                S[(row + 1) * A2S + c1]  = (unsigned short)(stB[rtp][i] >> 16);
                S[(row + 32) * A2S + c1] = (unsigned short)(stB[rtp][8 + i] & 0xFFFF);
                S[(row + 33) * A2S + c1] = (unsigned short)(stB[rtp][8 + i] >> 16);
            }
        }
    }
    __syncthreads();   // A2 ready

    // ---- GEMM2: ct-pair outer (B held, reused by both row-tile-pairs)
    const int cloud = batch[p0];
    #pragma unroll
    for (int cp = 0; cp < 2; ++cp) {
        const int ct0 = wave * 4 + cp * 2;
        const int n0 = ct0 * 32 + l31;
        const int n1 = (ct0 + 1) * 32 + l31;
        v8bf B2a[16], B2b[16];
        #pragma unroll
        for (int kc = 0; kc < 16; ++kc) {
            int c2 = kc * 2 + h;
            B2a[kc] = *(const v8bf*)(W4s + ((c2 * 512 + n0) << 3));
            B2b[kc] = *(const v8bf*)(W4s + ((c2 * 512 + n1) << 3));
        }
        float rm0 = -3.4e38f, rm1 = -3.4e38f;
        #pragma unroll
        for (int rtp = 0; rtp < 2; ++rtp) {
            v16f a00 = zero16(), a01 = zero16(), a10 = zero16(), a11 = zero16();
            #pragma unroll
            for (int kc = 0; kc < 16; ++kc) {
                v8bf a0 = *(const v8bf*)(S + (rtp * 64 + l31)      * A2S + kc * 16 + h * 8);
                v8bf a1 = *(const v8bf*)(S + (rtp * 64 + 32 + l31) * A2S + kc * 16 + h * 8);
                a00 = __builtin_amdgcn_mfma_f32_32x32x16_bf16(a0, B2a[kc], a00, 0, 0, 0);
                a10 = __builtin_amdgcn_mfma_f32_32x32x16_bf16(a1, B2a[kc], a10, 0, 0, 0);
                a01 = __builtin_amdgcn_mfma_f32_32x32x16_bf16(a0, B2b[kc], a01, 0, 0, 0);
                a11 = __builtin_amdgcn_mfma_f32_32x32x16_bf16(a1, B2b[kc], a11, 0, 0, 0);
            }
            #pragma unroll
            for (int r = 0; r < 16; ++r) {
                rm0 = fmaxf(rm0, fmaxf(a00[r], a10[r]));
                rm1 = fmaxf(rm1, fmaxf(a01[r], a11[r]));
            }
        }
        rm0 = fmaxf(rm0, __shfl_xor(rm0, 32));
        rm1 = fmaxf(rm1, __shfl_xor(rm1, 32));
        rm0 += b4[ct0 * 32 + l31];
        rm1 += b4[(ct0 + 1) * 32 + l31];
        if (lane < 32) {
            atomicMax(&encbuf[cloud * OUTC + ct0 * 32 + l31], fenc(rm0));
            atomicMax(&encbuf[cloud * OUTC + (ct0 + 1) * 32 + l31], fenc(rm1));
        }
    }
}

// ============================ finalize: decode encoded maxima ================
__global__ void finalize_kernel(const unsigned* __restrict__ encv,
                                float* __restrict__ out)
{
    int i = blockIdx.x * 256 + threadIdx.x;
    if (i < NCLOUD * OUTC) out[i] = fdec(encv[i]);
}

extern "C" void kernel_launch(void* const* d_in, const int* in_sizes, int n_in,
                              void* d_out, int out_size, void* d_ws, size_t ws_size,
                              hipStream_t stream)
{
    const float* pos   = (const float*)d_in[0];
    const int*   nbr   = (const int*)  d_in[1];
    const int*   batch = (const int*)  d_in[2];
    const float* W1    = (const float*)d_in[3];
    const float* b1    = (const float*)d_in[4];
    const float* W2    = (const float*)d_in[5];
    const float* b2    = (const float*)d_in[6];
    const float* W3    = (const float*)d_in[7];
    const float* b3    = (const float*)d_in[8];
    const float* W4    = (const float*)d_in[9];
    const float* b4    = (const float*)d_in[10];

    unsigned short* x1b = (unsigned short*)d_ws;                          // 8 MB
    unsigned short* W3s = (unsigned short*)((char*)d_ws + 8388608);       // 80 KB
    unsigned short* W4s = (unsigned short*)((char*)d_ws + 8470528);       // 256 KB
    unsigned*    encbuf = (unsigned*)((char*)d_ws + 8732672);             // 32 KB

    sa1_kernel<<<PTOT / 8, 256, 0, stream>>>(pos, nbr, W1, b1, W2, b2, W3, W4,
                                             W3s, W4s, encbuf, x1b);
    sa2_kernel<<<PTOT / 8, 256, 0, stream>>>(pos, nbr, batch, W3s, b3, W4s, b4,
                                             x1b, encbuf);
    finalize_kernel<<<(NCLOUD * OUTC + 255) / 256, 256, 0, stream>>>(encbuf, (float*)d_out);
}

// Round 19
// 244.360 us; speedup vs baseline: 2.0755x; 1.0133x over previous
//
#include <hip/hip_runtime.h>
#include <hip/hip_bf16.h>

#define PTOT   32768
#define KNB    16
#define NCLOUD 16
#define OUTC   512
#define A1S    168   // sa2 A1 row stride in ushort (336 B, 16B-aligned)
#define A2S    264   // sa2 A2 row stride in ushort (528 B, 16B-aligned)

typedef __attribute__((ext_vector_type(8)))  short v8bf;
typedef __attribute__((ext_vector_type(16))) float v16f;

__device__ __forceinline__ unsigned short f2b(float v) {
    __hip_bfloat16 h = __float2bfloat16(v);
    return *reinterpret_cast<unsigned short*>(&h);
}
__device__ __forceinline__ unsigned pk2(float a, float b) {
    return (unsigned)f2b(a) | ((unsigned)f2b(b) << 16);
}
__device__ __forceinline__ unsigned fenc(float f) {
    unsigned u = __float_as_uint(f);
    return (u & 0x80000000u) ? ~u : (u | 0x80000000u);
}
__device__ __forceinline__ float fdec(unsigned u) {
    unsigned b = (u & 0x80000000u) ? (u & 0x7FFFFFFFu) : ~u;
    return __uint_as_float(b);
}
__device__ __forceinline__ v16f zero16() {
    v16f z;
    #pragma unroll
    for (int i = 0; i < 16; ++i) z[i] = 0.0f;
    return z;
}

// ======= sa1 (MFMA) + absorbed prep: 8 points, single-pass M=128 ===========
// 2 barriers per block (was 6): stage 128 rows at once, G1 2 MFMAs/wave,
// G2 4 row-tiles/wave with held B2. All index formulas are the R8-proven
// patterns with rt extended 0..3. Blocks 0..671 transpose W3s/W4s; block
// 4095 zeroes encbuf. No device fences (R17 lesson).
__global__ __launch_bounds__(256) void sa1_kernel(
    const float* __restrict__ pos, const int* __restrict__ nbr,
    const float* __restrict__ W1, const float* __restrict__ b1,
    const float* __restrict__ W2, const float* __restrict__ b2,
    const float* __restrict__ W3, const float* __restrict__ W4,
    unsigned short* __restrict__ W3s, unsigned short* __restrict__ W4s,
    unsigned* __restrict__ encbuf,
    unsigned short* __restrict__ x1b)
{
    __shared__ unsigned short A1d[128 * 16];   // 4 KB
    __shared__ unsigned short A2[128 * 72];    // 18 KB
    const int tid  = threadIdx.x;
    const int lane = tid & 63;
    const int wave = tid >> 6;
    const int l31  = lane & 31;
    const int h    = lane >> 5;

    // ---- absorbed prep: W3s/W4s k-major bf16 images (blocks 0..671)
    {
        int ip = blockIdx.x * 256 + tid;
        if (ip < 40960) {                        // W3s[(c2*256+n)*8+j] = W3[c2*8+j][n]
            int j = ip & 7, n = (ip >> 3) & 255, c2 = ip >> 11;
            int k = c2 * 8 + j;
            W3s[ip] = f2b(k < 131 ? W3[k * 256 + n] : 0.0f);
        }
        int i2 = ip - 40960;
        if (i2 >= 0 && i2 < 131072) {            // W4s[(c2*512+n)*8+j] = W4[c2*8+j][n]
            int j = i2 & 7, n = (i2 >> 3) & 511, c2 = i2 >> 12;
            int k = c2 * 8 + j;
            W4s[i2] = f2b(W4[k * 512 + n]);
        }
        if (blockIdx.x == 4095) {                // encbuf init (fenc-domain -inf)
            for (int i = tid; i < NCLOUD * OUTC; i += 256) encbuf[i] = 0u;
        }
    }

    // ---- weight fragments from global fp32 (block-invariant)
    const int c1 = (wave >> 1) * 32 + l31;       // G1 col (col-tile = wave>>1)
    v8bf b1f;
    #pragma unroll
    for (int i = 0; i < 8; ++i) b1f[i] = 0;
    if (h == 0) {   // k=0..2 real, rest zero
        b1f[0] = (short)f2b(W1[c1]);
        b1f[1] = (short)f2b(W1[64 + c1]);
        b1f[2] = (short)f2b(W1[128 + c1]);
    }
    const float b1v = b1[c1];
    const int cW2 = wave * 32 + l31;             // G2 col (col-tile = wave)
    v8bf B2[4];
    #pragma unroll
    for (int kc = 0; kc < 4; ++kc)
        #pragma unroll
        for (int j = 0; j < 8; ++j)
            B2[kc][j] = (short)f2b(W2[(kc * 16 + h * 8 + j) * 128 + cW2]);
    const float b2v = b2[cW2];

    const int p0 = blockIdx.x * 8;

    // ---- stage A1d: 128 rows = (point, nbr), one thread per row
    if (tid < 128) {
        int r = tid;
        int j = nbr[p0 * KNB + r];
        int p = p0 + (r >> 4);
        v8bf z;
        #pragma unroll
        for (int i = 0; i < 8; ++i) z[i] = 0;
        v8bf dv = z;
        dv[0] = (short)f2b(pos[j * 3 + 0] - pos[p * 3 + 0]);
        dv[1] = (short)f2b(pos[j * 3 + 1] - pos[p * 3 + 1]);
        dv[2] = (short)f2b(pos[j * 3 + 2] - pos[p * 3 + 2]);
        *(v8bf*)(A1d + r * 16)     = dv;
        *(v8bf*)(A1d + r * 16 + 8) = z;
    }
    __syncthreads();

    // ---- G1: wave covers col-tile (wave>>1), row-tiles {wave&1, (wave&1)+2}
    #pragma unroll
    for (int rr = 0; rr < 2; ++rr) {
        const int rt = (wave & 1) + rr * 2;
        v8bf a = *(const v8bf*)(A1d + (rt * 32 + l31) * 16 + h * 8);
        v16f acc = __builtin_amdgcn_mfma_f32_32x32x16_bf16(a, b1f, zero16(), 0, 0, 0);
        #pragma unroll
        for (int r = 0; r < 16; ++r) {
            int row = rt * 32 + (r & 3) + 8 * (r >> 2) + 4 * h;
            A2[row * 72 + c1] = f2b(fmaxf(acc[r] + b1v, 0.0f));
        }
    }
    __syncthreads();

    // ---- G2: wave's col-tile over 4 row-tiles; per-rt max -> 2 points each
    #pragma unroll
    for (int rt = 0; rt < 4; ++rt) {
        v16f acc = zero16();
        #pragma unroll
        for (int kc = 0; kc < 4; ++kc) {
            v8bf a = *(const v8bf*)(A2 + (rt * 32 + l31) * 72 + kc * 16 + h * 8);
            acc = __builtin_amdgcn_mfma_f32_32x32x16_bf16(a, B2[kc], acc, 0, 0, 0);
        }
        float ma = acc[0], mb = acc[8];
        #pragma unroll
        for (int r = 1; r < 8; ++r) { ma = fmaxf(ma, acc[r]); mb = fmaxf(mb, acc[8 + r]); }
        ma = fmaxf(ma, __shfl_xor(ma, 32));
        mb = fmaxf(mb, __shfl_xor(mb, 32));
        int p = p0 + rt * 2 + h;
        float m = h ? mb : ma;
        x1b[p * 128 + cW2] = f2b(m + b2v);
    }
}

// ==== sa2 (MFMA): R16-proven body, byte-identical =========================
__global__ __launch_bounds__(256) void sa2_kernel(
    const float* __restrict__ pos, const int* __restrict__ nbr,
    const int* __restrict__ batch,
    const unsigned short* __restrict__ W3s, const float* __restrict__ b3,
    const unsigned short* __restrict__ W4s, const float* __restrict__ b4,
    const unsigned short* __restrict__ x1b, unsigned* __restrict__ encbuf)
{
    __shared__ unsigned short S[128 * A2S];   // 67584 B: A1 (stride A1S) overlaid
    const int tid  = threadIdx.x;
    const int lane = tid & 63;
    const int wave = tid >> 6;
    const int l31  = lane & 31;
    const int h    = lane >> 5;
    const int p0   = blockIdx.x * 8;

    const float b3v0 = b3[(wave * 2 + 0) * 32 + l31];
    const float b3v1 = b3[(wave * 2 + 1) * 32 + l31];

    // ---- stage A1: 128 rows = (point, nbr); 2 threads/row, 128 B each
    {
        int r = tid >> 1, q = tid & 1;
        int j = nbr[p0 * KNB + r];
        const uint4* src = (const uint4*)(x1b + j * 128 + q * 64);
        uint4* dst = (uint4*)(S + r * A1S + q * 64);
        #pragma unroll
        for (int i = 0; i < 8; ++i) dst[i] = src[i];
    }
    if (tid < 128) {
        int r = tid;
        int j = nbr[p0 * KNB + r];
        int p = p0 + (r >> 4);
        v8bf z;
        #pragma unroll
        for (int i = 0; i < 8; ++i) z[i] = 0;
        v8bf dv = z;
        dv[0] = (short)f2b(pos[j * 3 + 0] - pos[p * 3 + 0]);
        dv[1] = (short)f2b(pos[j * 3 + 1] - pos[p * 3 + 1]);
        dv[2] = (short)f2b(pos[j * 3 + 2] - pos[p * 3 + 2]);
        *(v8bf*)(S + r * A1S + 128) = dv;
        *(v8bf*)(S + r * A1S + 136) = z;
    }
    __syncthreads();

    // ---- GEMM1: kc-streamed B, looped over 2 row-tile-pairs; kc=9 pad skipped
    const int n1a = (wave * 2 + 0) * 32 + l31;
    const int n1b = (wave * 2 + 1) * 32 + l31;
    unsigned stA[2][16], stB[2][16];   // [rtp][..] ci=0 / ci=1
    #pragma unroll
    for (int rtp = 0; rtp < 2; ++rtp) {
        v16f g00 = zero16(), g01 = zero16(), g10 = zero16(), g11 = zero16();
        #pragma unroll
        for (int kc = 0; kc < 9; ++kc) {
            v8bf a0 = *(const v8bf*)(S + (rtp * 64 + l31)      * A1S + kc * 16 + h * 8);
            v8bf a1 = *(const v8bf*)(S + (rtp * 64 + 32 + l31) * A1S + kc * 16 + h * 8);
            int c2 = kc * 2 + h;
            v8bf B0 = *(const v8bf*)(W3s + ((c2 * 256 + n1a) << 3));
            v8bf B1 = *(const v8bf*)(W3s + ((c2 * 256 + n1b) << 3));
            g00 = __builtin_amdgcn_mfma_f32_32x32x16_bf16(a0, B0, g00, 0, 0, 0);
            g10 = __builtin_amdgcn_mfma_f32_32x32x16_bf16(a1, B0, g10, 0, 0, 0);
            g01 = __builtin_amdgcn_mfma_f32_32x32x16_bf16(a0, B1, g01, 0, 0, 0);
            g11 = __builtin_amdgcn_mfma_f32_32x32x16_bf16(a1, B1, g11, 0, 0, 0);
        }
        #pragma unroll
        for (int i = 0; i < 8; ++i) {
            stA[rtp][i]     = pk2(fmaxf(g00[2*i] + b3v0, 0.0f), fmaxf(g00[2*i+1] + b3v0, 0.0f));
            stA[rtp][8 + i] = pk2(fmaxf(g10[2*i] + b3v0, 0.0f), fmaxf(g10[2*i+1] + b3v0, 0.0f));
            stB[rtp][i]     = pk2(fmaxf(g01[2*i] + b3v1, 0.0f), fmaxf(g01[2*i+1] + b3v1, 0.0f));
            stB[rtp][8 + i] = pk2(fmaxf(g11[2*i] + b3v1, 0.0f), fmaxf(g11[2*i+1] + b3v1, 0.0f));
        }
    }
    __syncthreads();   // all A1 reads complete — safe to overwrite with A2

    // ---- store A2 = bf16(relu(GEMM1)) row-major, stride A2S
    {
        const int c0 = (wave * 2 + 0) * 32 + l31;
        const int c1 = (wave * 2 + 1) * 32 + l31;
        #pragma unroll
        for (int rtp = 0; rtp < 2; ++rtp) {
            const int rb = rtp * 64;
            #pragma unroll
            for (int i = 0; i < 8; ++i) {
                int row = rb + ((2*i) & 3) + 8 * ((2*i) >> 2) + 4 * h;
                S[row * A2S + c0]        = (unsigned short)(stA[rtp][i] & 0xFFFF);
                S[(row + 1) * A2S + c0]  = (unsigned short)(stA[rtp][i] >> 16);
                S[(row + 32) * A2S + c0] = (unsigned short)(stA[rtp][8 + i] & 0xFFFF);
                S[(row + 33) * A2S + c0] = (unsigned short)(stA[rtp][8 + i] >> 16);
                S[row * A2S + c1]        = (unsigned short)(stB[rtp][i] & 0xFFFF);
                S[(row + 1) * A2S + c1]  = (unsigned short)(stB[rtp][i] >> 16);
                S[(row + 32) * A2S + c1] = (unsigned short)(stB[rtp][8 + i] & 0xFFFF);
                S[(row + 33) * A2S + c1] = (unsigned short)(stB[rtp][8 + i] >> 16);
            }
        }
    }
    __syncthreads();   // A2 ready

    // ---- GEMM2: ct-pair outer (B held, reused by both row-tile-pairs)
    const int cloud = batch[p0];
    #pragma unroll
    for (int cp = 0; cp < 2; ++cp) {
        const int ct0 = wave * 4 + cp * 2;
        const int n0 = ct0 * 32 + l31;
        const int n1 = (ct0 + 1) * 32 + l31;
        v8bf B2a[16], B2b[16];
        #pragma unroll
        for (int kc = 0; kc < 16; ++kc) {
            int c2 = kc * 2 + h;
            B2a[kc] = *(const v8bf*)(W4s + ((c2 * 512 + n0) << 3));
            B2b[kc] = *(const v8bf*)(W4s + ((c2 * 512 + n1) << 3));
        }
        float rm0 = -3.4e38f, rm1 = -3.4e38f;
        #pragma unroll
        for (int rtp = 0; rtp < 2; ++rtp) {
            v16f a00 = zero16(), a01 = zero16(), a10 = zero16(), a11 = zero16();
            #pragma unroll
            for (int kc = 0; kc < 16; ++kc) {
                v8bf a0 = *(const v8bf*)(S + (rtp * 64 + l31)      * A2S + kc * 16 + h * 8);
                v8bf a1 = *(const v8bf*)(S + (rtp * 64 + 32 + l31) * A2S + kc * 16 + h * 8);
                a00 = __builtin_amdgcn_mfma_f32_32x32x16_bf16(a0, B2a[kc], a00, 0, 0, 0);
                a10 = __builtin_amdgcn_mfma_f32_32x32x16_bf16(a1, B2a[kc], a10, 0, 0, 0);
                a01 = __builtin_amdgcn_mfma_f32_32x32x16_bf16(a0, B2b[kc], a01, 0, 0, 0);
                a11 = __builtin_amdgcn_mfma_f32_32x32x16_bf16(a1, B2b[kc], a11, 0, 0, 0);
            }
            #pragma unroll
            for (int r = 0; r < 16; ++r) {
                rm0 = fmaxf(rm0, fmaxf(a00[r], a10[r]));
                rm1 = fmaxf(rm1, fmaxf(a01[r], a11[r]));
            }
        }
        rm0 = fmaxf(rm0, __shfl_xor(rm0, 32));
        rm1 = fmaxf(rm1, __shfl_xor(rm1, 32));
        rm0 += b4[ct0 * 32 + l31];
        rm1 += b4[(ct0 + 1) * 32 + l31];
        if (lane < 32) {
            atomicMax(&encbuf[cloud * OUTC + ct0 * 32 + l31], fenc(rm0));
            atomicMax(&encbuf[cloud * OUTC + (ct0 + 1) * 32 + l31], fenc(rm1));
        }
    }
}

// ============================ finalize: decode encoded maxima ================
__global__ void finalize_kernel(const unsigned* __restrict__ encv,
                                float* __restrict__ out)
{
    int i = blockIdx.x * 256 + threadIdx.x;
    if (i < NCLOUD * OUTC) out[i] = fdec(encv[i]);
}

extern "C" void kernel_launch(void* const* d_in, const int* in_sizes, int n_in,
                              void* d_out, int out_size, void* d_ws, size_t ws_size,
                              hipStream_t stream)
{
    const float* pos   = (const float*)d_in[0];
    const int*   nbr   = (const int*)  d_in[1];
    const int*   batch = (const int*)  d_in[2];
    const float* W1    = (const float*)d_in[3];
    const float* b1    = (const float*)d_in[4];
    const float* W2    = (const float*)d_in[5];
    const float* b2    = (const float*)d_in[6];
    const float* W3    = (const float*)d_in[7];
    const float* b3    = (const float*)d_in[8];
    const float* W4    = (const float*)d_in[9];
    const float* b4    = (const float*)d_in[10];

    unsigned short* x1b = (unsigned short*)d_ws;                          // 8 MB
    unsigned short* W3s = (unsigned short*)((char*)d_ws + 8388608);       // 80 KB
    unsigned short* W4s = (unsigned short*)((char*)d_ws + 8470528);       // 256 KB
    unsigned*    encbuf = (unsigned*)((char*)d_ws + 8732672);             // 32 KB

    sa1_kernel<<<PTOT / 8, 256, 0, stream>>>(pos, nbr, W1, b1, W2, b2, W3, W4,
                                             W3s, W4s, encbuf, x1b);
    sa2_kernel<<<PTOT / 8, 256, 0, stream>>>(pos, nbr, batch, W3s, b3, W4s, b4,
                                             x1b, encbuf);
    finalize_kernel<<<(NCLOUD * OUTC + 255) / 256, 256, 0, stream>>>(encbuf, (float*)d_out);
}